// Round 1
// baseline (250.198 us; speedup 1.0000x reference)
//
#include <hip/hip_runtime.h>
#include <hip/hip_fp16.h>

// InvariantGaussianAttention, MI355X (gfx950)
// B=2 N=384 CS=384 CZ=128 H=8 CH=16 G=2 P=8 CZ4=32
#define NB   2
#define NN   384
#define NCS  384
#define NCZ  128
#define NH   8
#define NCH  16
#define NG   2
#define NP   8
#define NCZ4 32
#define BN   (NB*NN)   // 768
#define LINW 768       // q(128)|k(128)|v(128)|qg(96)|kg(96)|vp(192)

typedef _Float16 f16x2_t __attribute__((ext_vector_type(2)));

static __device__ __forceinline__ float fdot2a(unsigned int a, unsigned int b, float c) {
#if __has_builtin(__builtin_amdgcn_fdot2)
    return __builtin_amdgcn_fdot2(__builtin_bit_cast(f16x2_t, a),
                                  __builtin_bit_cast(f16x2_t, b), c, false);
#else
    __half2 ah = __builtin_bit_cast(__half2, a);
    __half2 bh = __builtin_bit_cast(__half2, b);
    float2 af = __half22float2(ah), bf = __half22float2(bh);
    return fmaf(af.y, bf.y, fmaf(af.x, bf.x, c));
#endif
}

// ---------------- K0: pack [Wb | Wdz] columns as half2 (c-pairs) ----------------
__global__ void k_wprep(const float* __restrict__ Wb, const float* __restrict__ Wdz,
                        unsigned int* __restrict__ wc) {
    int t = threadIdx.x;
    for (int e = t; e < 40*64; e += 256) {
        int oc = e >> 6, c2 = e & 63;
        float w0, w1;
        if (oc < 8) { w0 = Wb[(2*c2)*NH + oc];       w1 = Wb[(2*c2+1)*NH + oc]; }
        else        { int c4 = oc-8;
                      w0 = Wdz[(2*c2)*NCZ4 + c4];    w1 = Wdz[(2*c2+1)*NCZ4 + c4]; }
        __half2 h = __floats2half2_rn(w0, w1);
        wc[e] = __builtin_bit_cast(unsigned int, h);
    }
}

// ---------------- K1: fused row linear  lin = s @ [Wq|Wk|Wv|Wqg|Wkg|Wvp] ----------------
__global__ void k_rowlin(const float* __restrict__ s,
                         const float* __restrict__ Wq, const float* __restrict__ Wk,
                         const float* __restrict__ Wv,
                         const float* __restrict__ Wqg, const float* __restrict__ bqg,
                         const float* __restrict__ Wkg, const float* __restrict__ bkg,
                         const float* __restrict__ Wvp, const float* __restrict__ bvp,
                         float* __restrict__ lin) {
    __shared__ float sl[4][NCS];
    int t  = threadIdx.x;
    int r0 = blockIdx.x * 4;
    for (int idx = t; idx < 4*NCS; idx += 256)
        sl[idx / NCS][idx % NCS] = s[(size_t)(r0 + idx/NCS)*NCS + (idx % NCS)];
    __syncthreads();
    int col = blockIdx.y * 256 + t;
    const float* W; int sw; float bias = 0.f;
    if      (col < 128) { W = Wq  + col;        sw = 128; }
    else if (col < 256) { W = Wk  + (col-128);  sw = 128; }
    else if (col < 384) { W = Wv  + (col-256);  sw = 128; }
    else if (col < 480) { W = Wqg + (col-384);  sw = 96;  bias = bqg[col-384]; }
    else if (col < 576) { W = Wkg + (col-480);  sw = 96;  bias = bkg[col-480]; }
    else                { W = Wvp + (col-576);  sw = 192; bias = bvp[col-576]; }
    float a0=0.f, a1=0.f, a2=0.f, a3=0.f;
    for (int c = 0; c < NCS; ++c) {
        float w = W[(size_t)c*sw];
        a0 = fmaf(sl[0][c], w, a0);
        a1 = fmaf(sl[1][c], w, a1);
        a2 = fmaf(sl[2][c], w, a2);
        a3 = fmaf(sl[3][c], w, a3);
    }
    lin[(size_t)(r0+0)*LINW + col] = a0 + bias;
    lin[(size_t)(r0+1)*LINW + col] = a1 + bias;
    lin[(size_t)(r0+2)*LINW + col] = a2 + bias;
    lin[(size_t)(r0+3)*LINW + col] = a3 + bias;
}

// ---------------- K2: to_global (mu, Sigma) for q/k sides + rotated value points ----------------
__global__ void k_geom(const float* __restrict__ lin, const float* __restrict__ rot,
                       const float* __restrict__ trans, const float* __restrict__ lm,
                       const float* __restrict__ sc,
                       float* __restrict__ qmu, float* __restrict__ qsig,
                       float* __restrict__ kmu, float* __restrict__ ksig,
                       float* __restrict__ vpg) {
    int bn = blockIdx.x, t = threadIdx.x;
    __shared__ float R[9], T[3], A[3], Bs[3];
    if (t < 9) R[t] = rot[bn*9 + t];
    if (t < 3) { T[t] = trans[bn*3+t]; A[t] = lm[bn*3+t]; Bs[t] = sc[bn*3+t]; }
    __syncthreads();
    {   // value points: one per thread (h=t/8, p=t&7)
        int h = t >> 3, p = t & 7;
        const float* vr = lin + (size_t)bn*LINW + 576 + h*24 + p*3;
        float x = vr[0], y = vr[1], z = vr[2];
        float* d = vpg + (size_t)bn*(NH*NP*3) + h*24 + p*3;
        d[0] = R[0]*x + R[1]*y + R[2]*z + T[0];
        d[1] = R[3]*x + R[4]*y + R[5]*z + T[1];
        d[2] = R[6]*x + R[7]*y + R[8]*z + T[2];
    }
    if (t < 32) {
        int side = t >> 4, item = t & 15;      // item = h*2+g
        const float* raw = lin + (size_t)bn*LINW + (side ? 480 : 384) + item*6;
        float u0 = tanhf(raw[0])*3.f, u1 = tanhf(raw[1])*3.f, u2 = tanhf(raw[2])*3.f;
        float e0 = Bs[0] + tanhf(raw[3])*2.f;
        float e1 = Bs[1] + tanhf(raw[4])*2.f;
        float e2 = Bs[2] + tanhf(raw[5])*2.f;
        float sl0 = fmaxf(expf(e0), 1e-6f);
        float sl1 = fmaxf(expf(e1), 1e-6f);
        float sl2 = fmaxf(expf(e2), 1e-6f);
        float p0 = A[0] + u0*sl0, p1 = A[1] + u1*sl1, p2 = A[2] + u2*sl2;
        float mu0 = R[0]*p0 + R[1]*p1 + R[2]*p2 + T[0];
        float mu1 = R[3]*p0 + R[4]*p1 + R[5]*p2 + T[1];
        float mu2 = R[6]*p0 + R[7]*p1 + R[8]*p2 + T[2];
        float v0 = expf(2.f*e0), v1 = expf(2.f*e1), v2 = expf(2.f*e2);
        float s00 = R[0]*R[0]*v0 + R[1]*R[1]*v1 + R[2]*R[2]*v2;
        float s01 = R[0]*R[3]*v0 + R[1]*R[4]*v1 + R[2]*R[5]*v2;
        float s02 = R[0]*R[6]*v0 + R[1]*R[7]*v1 + R[2]*R[8]*v2;
        float s11 = R[3]*R[3]*v0 + R[4]*R[4]*v1 + R[5]*R[5]*v2;
        float s12 = R[3]*R[6]*v0 + R[4]*R[7]*v1 + R[5]*R[8]*v2;
        float s22 = R[6]*R[6]*v0 + R[7]*R[7]*v1 + R[8]*R[8]*v2;
        float* mud = (side ? kmu : qmu) + (size_t)bn*48 + item*3;
        mud[0]=mu0; mud[1]=mu1; mud[2]=mu2;
        float* sgd = (side ? ksig : qsig) + (size_t)bn*96 + item*6;
        sgd[0]=s00; sgd[1]=s01; sgd[2]=s02; sgd[3]=s11; sgd[4]=s12; sgd[5]=s22;
    }
}

// ---------------- K3: fused attention, one block per (b,i), z streamed once ----------------
__global__ void __launch_bounds__(256)
k_attn(const float* __restrict__ z, const float* __restrict__ mask,
       const float* __restrict__ rot, const float* __restrict__ trans,
       const float* __restrict__ lin,
       const float* __restrict__ qmu, const float* __restrict__ qsig,
       const float* __restrict__ kmu, const float* __restrict__ ksig,
       const float* __restrict__ vpg, const unsigned int* __restrict__ wc,
       const float* __restrict__ bb, const float* __restrict__ bdz,
       const float* __restrict__ gsc, const float* __restrict__ gbi,
       float* __restrict__ cat) {
    __shared__ float  logits[NH][NN];           // 12 KB
    __shared__ unsigned short zh[24][128];      // 6 KB (f16 z chunk)
    __shared__ __half pzl[NN][36];              // 27.65 KB (pz row, padded stride)
    __shared__ float  qrow[128];
    __shared__ float  qmu_s[48], qsig_s[96];
    __shared__ float  Rm[9], Tv[3];
    __shared__ float  aH[NH], bH[NH];
    __shared__ float  maskI;

    int t  = threadIdx.x;
    int b  = blockIdx.x / NN, i = blockIdx.x % NN;
    int bi = b*NN + i;

    if (t < 128) qrow[t] = lin[(size_t)bi*LINW + t];
    if (t < 48)  qmu_s[t] = qmu[(size_t)bi*48 + t];
    if (t >= 64 && t < 160) qsig_s[t-64] = qsig[(size_t)bi*96 + (t-64)];
    if (t >= 160 && t < 169) Rm[t-160] = rot[bi*9 + (t-160)];
    if (t >= 169 && t < 172) Tv[t-169] = trans[bi*3 + (t-169)];
    if (t >= 176 && t < 184) {
        int h = t-176;
        float x = gsc[h];
        aH[h] = (x > 20.f) ? x : log1pf(expf(x));
        bH[h] = gbi[h];
    }
    if (t == 255) maskI = mask[bi];

    // z-dot assignment: 240 threads, oc in [0,40), 6 j-groups of 4
    int oc = t % 40, g6 = t / 40;
    float biasv = 0.f;
    if (t < 240) biasv = (oc < 8) ? bb[oc] : bdz[oc-8];
    const unsigned int* wrow = wc + oc*64;
    const float* zbase = z + (size_t)bi*NN*NCZ;

    for (int ch = 0; ch < 16; ++ch) {
        int j0 = ch*24;
        // --- A: stage z chunk (24 j x 128 c) as f16 ---
        const float* zp = zbase + (size_t)j0*NCZ;
        #pragma unroll
        for (int rep = 0; rep < 3; ++rep) {
            int idx = rep*1024 + t*4;
            float4 zv = *reinterpret_cast<const float4*>(zp + idx);
            int j = idx >> 7, c = idx & 127;
            __half2* dst = reinterpret_cast<__half2*>(&zh[j][c]);
            dst[0] = __floats2half2_rn(zv.x, zv.y);
            dst[1] = __floats2half2_rn(zv.z, zv.w);
        }
        __syncthreads();
        // --- B: z @ [Wb|Wdz] via v_dot2_f32_f16; zb -> logits, pz -> LDS ---
        if (t < 240) {
            float a0=0.f, a1=0.f, a2=0.f, a3=0.f;
            int jb = g6*4;
            #pragma unroll
            for (int q = 0; q < 16; ++q) {
                uint4 wv = *reinterpret_cast<const uint4*>(wrow + q*4);
                uint4 z0 = *reinterpret_cast<const uint4*>(&zh[jb+0][q*8]);
                uint4 z1 = *reinterpret_cast<const uint4*>(&zh[jb+1][q*8]);
                uint4 z2 = *reinterpret_cast<const uint4*>(&zh[jb+2][q*8]);
                uint4 z3 = *reinterpret_cast<const uint4*>(&zh[jb+3][q*8]);
                a0 = fdot2a(z0.x, wv.x, a0); a0 = fdot2a(z0.y, wv.y, a0);
                a0 = fdot2a(z0.z, wv.z, a0); a0 = fdot2a(z0.w, wv.w, a0);
                a1 = fdot2a(z1.x, wv.x, a1); a1 = fdot2a(z1.y, wv.y, a1);
                a1 = fdot2a(z1.z, wv.z, a1); a1 = fdot2a(z1.w, wv.w, a1);
                a2 = fdot2a(z2.x, wv.x, a2); a2 = fdot2a(z2.y, wv.y, a2);
                a2 = fdot2a(z2.z, wv.z, a2); a2 = fdot2a(z2.w, wv.w, a2);
                a3 = fdot2a(z3.x, wv.x, a3); a3 = fdot2a(z3.y, wv.y, a3);
                a3 = fdot2a(z3.z, wv.z, a3); a3 = fdot2a(z3.w, wv.w, a3);
            }
            if (oc < 8) {
                logits[oc][j0+jb+0] = a0 + biasv;
                logits[oc][j0+jb+1] = a1 + biasv;
                logits[oc][j0+jb+2] = a2 + biasv;
                logits[oc][j0+jb+3] = a3 + biasv;
            } else {
                int c4 = oc - 8;
                pzl[j0+jb+0][c4] = __float2half(a0 + biasv);
                pzl[j0+jb+1][c4] = __float2half(a1 + biasv);
                pzl[j0+jb+2][c4] = __float2half(a2 + biasv);
                pzl[j0+jb+3][c4] = __float2half(a3 + biasv);
            }
        }
        __syncthreads();
        // --- C: qk + geo NLL -> logits ---
        {
            int h = t >> 5, lane = t & 31;
            if (lane < 24) {
                int j = j0 + lane;
                size_t jrow = (size_t)(b*NN + j);
                const float* kp = lin + jrow*LINW + 128 + h*NCH;
                float4 k0 = *(const float4*)(kp);
                float4 k1 = *(const float4*)(kp+4);
                float4 k2 = *(const float4*)(kp+8);
                float4 k3 = *(const float4*)(kp+12);
                const float* qp = &qrow[h*NCH];
                float qk = qp[0]*k0.x + qp[1]*k0.y + qp[2]*k0.z + qp[3]*k0.w
                         + qp[4]*k1.x + qp[5]*k1.y + qp[6]*k1.z + qp[7]*k1.w
                         + qp[8]*k2.x + qp[9]*k2.y + qp[10]*k2.z + qp[11]*k2.w
                         + qp[12]*k3.x + qp[13]*k3.y + qp[14]*k3.z + qp[15]*k3.w;
                float geo = 0.f;
                #pragma unroll
                for (int g = 0; g < NG; ++g) {
                    const float* km = kmu + jrow*48 + h*6 + g*3;
                    const float* ks = ksig + jrow*96 + h*12 + g*6;
                    float d0 = qmu_s[h*6+g*3+0] - km[0];
                    float d1 = qmu_s[h*6+g*3+1] - km[1];
                    float d2 = qmu_s[h*6+g*3+2] - km[2];
                    float s00 = qsig_s[h*12+g*6+0] + ks[0];
                    float s01 = qsig_s[h*12+g*6+1] + ks[1];
                    float s02 = qsig_s[h*12+g*6+2] + ks[2];
                    float s11 = qsig_s[h*12+g*6+3] + ks[3];
                    float s12 = qsig_s[h*12+g*6+4] + ks[4];
                    float s22 = qsig_s[h*12+g*6+5] + ks[5];
                    float l00 = fmaxf(s00, 1e-8f);
                    float i00 = rsqrtf(l00);
                    float l10 = s01*i00, l20 = s02*i00;
                    float l11 = fmaxf(s11 - l10*l10, 1e-8f);
                    float i11 = rsqrtf(l11);
                    float l21 = (s12 - l20*l10)*i11;
                    float l22 = fmaxf(s22 - l20*l20 - l21*l21, 1e-8f);
                    float i22 = rsqrtf(l22);
                    float ld = __logf(l00) + __logf(l11) + __logf(l22);
                    float y0 = d0*i00;
                    float y1 = (d1 - l10*y0)*i11;
                    float y2 = (d2 - l20*y0 - l21*y1)*i22;
                    geo += -0.5f*(y0*y0 + y1*y1 + y2*y2 + ld);
                }
                float mj = mask[b*NN + j];
                float m2 = maskI * mj;
                logits[h][j] += qk*0.25f + aH[h]*(geo*m2) + bH[h] + (1.f - m2)*(-100000.f);
            }
        }
        __syncthreads();
    }

    // --- softmax per head (32 lanes per head) ---
    int h = t >> 5, lane = t & 31;
    float mx = -3.4e38f;
    #pragma unroll
    for (int jj = 0; jj < 12; ++jj) mx = fmaxf(mx, logits[h][lane + jj*32]);
    #pragma unroll
    for (int m = 16; m >= 1; m >>= 1) mx = fmaxf(mx, __shfl_xor(mx, m, 64));
    float se = 0.f;
    #pragma unroll
    for (int jj = 0; jj < 12; ++jj) {
        int j = lane + jj*32;
        float e = __expf(logits[h][j] - mx);
        logits[h][j] = e;
        se += e;
    }
    #pragma unroll
    for (int m = 16; m >= 1; m >>= 1) se += __shfl_xor(se, m, 64);
    float inv = 1.f / se;

    // --- pass 2: o / opt / opair accumulation ---
    float o[16], op[24], opa[32];
    #pragma unroll
    for (int d = 0; d < 16; ++d) o[d] = 0.f;
    #pragma unroll
    for (int e = 0; e < 24; ++e) op[e] = 0.f;
    #pragma unroll
    for (int c = 0; c < 32; ++c) opa[c] = 0.f;

    for (int jj = 0; jj < 12; ++jj) {
        int j = lane + jj*32;
        float w = logits[h][j] * inv;
        size_t jrow = (size_t)(b*NN + j);
        const float* vp = lin + jrow*LINW + 256 + h*NCH;
        float vv[16];
        *reinterpret_cast<float4*>(&vv[0])  = *(const float4*)(vp);
        *reinterpret_cast<float4*>(&vv[4])  = *(const float4*)(vp+4);
        *reinterpret_cast<float4*>(&vv[8])  = *(const float4*)(vp+8);
        *reinterpret_cast<float4*>(&vv[12]) = *(const float4*)(vp+12);
        #pragma unroll
        for (int d = 0; d < 16; ++d) o[d] = fmaf(w, vv[d], o[d]);
        const float* vg = vpg + jrow*(NH*NP*3) + h*24;
        float gg[24];
        #pragma unroll
        for (int q4 = 0; q4 < 6; ++q4)
            *reinterpret_cast<float4*>(&gg[q4*4]) = *(const float4*)(vg + q4*4);
        #pragma unroll
        for (int e = 0; e < 24; ++e) op[e] = fmaf(w, gg[e], op[e]);
        const __half2* pzp = reinterpret_cast<const __half2*>(&pzl[j][0]);
        #pragma unroll
        for (int c2 = 0; c2 < 16; ++c2) {
            float2 pf = __half22float2(pzp[c2]);
            opa[2*c2]   = fmaf(w, pf.x, opa[2*c2]);
            opa[2*c2+1] = fmaf(w, pf.y, opa[2*c2+1]);
        }
    }
    // butterfly reduce across the 32 lanes of this head
    #pragma unroll
    for (int m = 16; m >= 1; m >>= 1) {
        #pragma unroll
        for (int d = 0; d < 16; ++d) o[d] += __shfl_xor(o[d], m, 64);
        #pragma unroll
        for (int e = 0; e < 24; ++e) op[e] += __shfl_xor(op[e], m, 64);
        #pragma unroll
        for (int c = 0; c < 32; ++c) opa[c] += __shfl_xor(opa[c], m, 64);
    }
    if (lane == 0) {
        float* cp = cat + (size_t)bi*640;
        #pragma unroll
        for (int d = 0; d < 16; ++d) cp[h*16 + d] = o[d];
        #pragma unroll
        for (int p = 0; p < 8; ++p) {
            float x  = op[p*3+0] - Tv[0];
            float y  = op[p*3+1] - Tv[1];
            float zz = op[p*3+2] - Tv[2];
            float l0 = Rm[0]*x + Rm[3]*y + Rm[6]*zz;   // R^T * (opt - trans)
            float l1 = Rm[1]*x + Rm[4]*y + Rm[7]*zz;
            float l2 = Rm[2]*x + Rm[5]*y + Rm[8]*zz;
            cp[128 + h*24 + p*3 + 0] = l0;
            cp[128 + h*24 + p*3 + 1] = l1;
            cp[128 + h*24 + p*3 + 2] = l2;
            cp[320 + h*8 + p] = sqrtf(l0*l0 + l1*l1 + l2*l2 + 1e-8f);
        }
        #pragma unroll
        for (int c = 0; c < 32; ++c) cp[384 + h*32 + c] = opa[c];
    }
}

// ---------------- K4: out = cat @ Wout + bout ----------------
__global__ void k_out(const float* __restrict__ cat, const float* __restrict__ Wout,
                      const float* __restrict__ bout, float* __restrict__ out) {
    __shared__ float cl[4][640];
    int t  = threadIdx.x;
    int r0 = blockIdx.x * 4;
    for (int idx = t; idx < 4*640; idx += 384)
        cl[idx/640][idx%640] = cat[(size_t)(r0 + idx/640)*640 + (idx%640)];
    __syncthreads();
    int col = t;  // 384 threads == 384 cols
    float a0=0.f, a1=0.f, a2=0.f, a3=0.f;
    for (int c = 0; c < 640; ++c) {
        float w = Wout[(size_t)c*NCS + col];
        a0 = fmaf(cl[0][c], w, a0);
        a1 = fmaf(cl[1][c], w, a1);
        a2 = fmaf(cl[2][c], w, a2);
        a3 = fmaf(cl[3][c], w, a3);
    }
    float bv = bout[col];
    out[(size_t)(r0+0)*NCS + col] = a0 + bv;
    out[(size_t)(r0+1)*NCS + col] = a1 + bv;
    out[(size_t)(r0+2)*NCS + col] = a2 + bv;
    out[(size_t)(r0+3)*NCS + col] = a3 + bv;
}

extern "C" void kernel_launch(void* const* d_in, const int* in_sizes, int n_in,
                              void* d_out, int out_size, void* d_ws, size_t ws_size,
                              hipStream_t stream) {
    const float* s    = (const float*)d_in[0];
    const float* z    = (const float*)d_in[1];
    const float* mask = (const float*)d_in[2];
    const float* rot  = (const float*)d_in[3];
    const float* trans= (const float*)d_in[4];
    const float* lm   = (const float*)d_in[5];
    const float* sc   = (const float*)d_in[6];
    const float* Wq   = (const float*)d_in[7];
    const float* Wk   = (const float*)d_in[8];
    const float* Wv   = (const float*)d_in[9];
    const float* Wb   = (const float*)d_in[10];
    const float* bb   = (const float*)d_in[11];
    const float* Wdz  = (const float*)d_in[12];
    const float* bdz  = (const float*)d_in[13];
    const float* Wqg  = (const float*)d_in[14];
    const float* bqg  = (const float*)d_in[15];
    const float* Wkg  = (const float*)d_in[16];
    const float* bkg  = (const float*)d_in[17];
    const float* Wvp  = (const float*)d_in[18];
    const float* bvp  = (const float*)d_in[19];
    const float* gsc  = (const float*)d_in[20];
    const float* gbi  = (const float*)d_in[21];
    const float* Wout = (const float*)d_in[22];
    const float* bout = (const float*)d_in[23];
    float* out = (float*)d_out;

    float* ws   = (float*)d_ws;
    float* lin  = ws;                    // 768*768      = 589824
    float* qmu  = lin  + 589824;         // 768*48       = 36864
    float* qsig = qmu  + 36864;          // 768*96       = 73728
    float* kmu  = qsig + 73728;          // 36864
    float* ksig = kmu  + 36864;          // 73728
    float* vpg  = ksig + 73728;          // 768*192      = 147456
    float* cat  = vpg  + 147456;         // 768*640      = 491520
    unsigned int* wc = (unsigned int*)(cat + 491520);   // 40*64 = 2560 u32

    k_wprep<<<1, 256, 0, stream>>>(Wb, Wdz, wc);
    k_rowlin<<<dim3(192, 3), 256, 0, stream>>>(s, Wq, Wk, Wv, Wqg, bqg, Wkg, bkg,
                                               Wvp, bvp, lin);
    k_geom<<<BN, 64, 0, stream>>>(lin, rot, trans, lm, sc, qmu, qsig, kmu, ksig, vpg);
    k_attn<<<BN, 256, 0, stream>>>(z, mask, rot, trans, lin, qmu, qsig, kmu, ksig,
                                   vpg, wc, bb, bdz, gsc, gbi, cat);
    k_out<<<192, 384, 0, stream>>>(cat, Wout, bout, out);
}